// Round 1
// baseline (7200.429 us; speedup 1.0000x reference)
//
#include <hip/hip_runtime.h>
#include <stdint.h>

#define TN_D 1024
#define TN_F 1024
#define SENT 0xAAAAAAAAu

__device__ __forceinline__ float dot4(float4 a, float4 b) {
    return a.x * b.x + a.y * b.y + a.z * b.z + a.w * b.w;
}

// ---------------------------------------------------------------------------
// Transpose core[s][i][j] -> coreT[s][j][i] so each column is contiguous.
// block = (32,8), grid = (32 j-tiles, 32 i-tiles, nsym)
// ---------------------------------------------------------------------------
__global__ __launch_bounds__(256) void tn_transpose(const float* __restrict__ core,
                                                    float* __restrict__ coreT) {
    __shared__ float tile[32][33];  // +1 pad: conflict-free transpose
    const int s = blockIdx.z;
    const size_t base = (size_t)s * TN_D * TN_D;
    const int j0 = blockIdx.x * 32;
    const int i0 = blockIdx.y * 32;
    const int tx = threadIdx.x;  // 0..31
    const int ty = threadIdx.y;  // 0..7
#pragma unroll
    for (int r = 0; r < 4; ++r) {
        int ii = ty + 8 * r;
        tile[ii][tx] = core[base + (size_t)(i0 + ii) * TN_D + (j0 + tx)];
    }
    __syncthreads();
#pragma unroll
    for (int r = 0; r < 4; ++r) {
        int jj = ty + 8 * r;
        coreT[base + (size_t)(j0 + jj) * TN_D + (i0 + tx)] = tile[tx][jj];
    }
}

// ---------------------------------------------------------------------------
// Persistent chain kernel. 256 blocks x 256 threads (4 waves). Wave w of
// block b owns column j = 4b + w. Data-flow sync: step-t output values are
// published with agent-scope atomic stores; consumers spin until the value
// is no longer the 0xAA poison sentinel (all true values are > 0, sentinel
// is a negative float, so no collision is possible).
// ---------------------------------------------------------------------------
template <bool TR>
__global__ __launch_bounds__(256, 1) void tn_chain(const int* __restrict__ x,
                                                   const float* __restrict__ mat,
                                                   const float* __restrict__ left,
                                                   const float* __restrict__ right,
                                                   float* __restrict__ vbuf,
                                                   float* __restrict__ out) {
    const int w = threadIdx.x >> 6;   // wave 0..3
    const int l = threadIdx.x & 63;   // lane
    const int j = blockIdx.x * 4 + w; // owned column

    float4 m[4];
    {   // prefetch step-0 matrix column
        int s = x[0];
        if (TR) {
            const float4* mp = (const float4*)(mat + ((size_t)s * TN_D + j) * TN_D);
            m[0] = mp[l]; m[1] = mp[l + 64]; m[2] = mp[l + 128]; m[3] = mp[l + 192];
        } else {
            const float* mp = mat + (size_t)s * TN_D * TN_D + j;
#pragma unroll
            for (int k = 0; k < 4; ++k) {
                int i = 4 * l + 256 * k;
                m[k] = make_float4(mp[(size_t)i * TN_D], mp[(size_t)(i + 1) * TN_D],
                                   mp[(size_t)(i + 2) * TN_D], mp[(size_t)(i + 3) * TN_D]);
            }
        }
    }

    for (int t = 0; t < TN_F; ++t) {
        // ---- prefetch next step's matrix column (independent of the sync) ----
        float4 n[4];
        {
            int s2 = x[(t + 1 < TN_F) ? t + 1 : 0];
            if (TR) {
                const float4* mp = (const float4*)(mat + ((size_t)s2 * TN_D + j) * TN_D);
                n[0] = mp[l]; n[1] = mp[l + 64]; n[2] = mp[l + 128]; n[3] = mp[l + 192];
            } else {
                const float* mp = mat + (size_t)s2 * TN_D * TN_D + j;
#pragma unroll
                for (int k = 0; k < 4; ++k) {
                    int i = 4 * l + 256 * k;
                    n[k] = make_float4(mp[(size_t)i * TN_D], mp[(size_t)(i + 1) * TN_D],
                                       mp[(size_t)(i + 2) * TN_D], mp[(size_t)(i + 3) * TN_D]);
                }
            }
        }

        // ---- obtain v_t (poll previous step's published values) ----
        float4 v[4];
        if (t == 0) {
            const float4* vp = (const float4*)left;
            v[0] = vp[l]; v[1] = vp[l + 64]; v[2] = vp[l + 128]; v[3] = vp[l + 192];
        } else {
            const uint32_t* vp = (const uint32_t*)vbuf + (size_t)(t - 1) * TN_D;
            uint32_t u[16];
            bool done;
            do {
                done = true;
#pragma unroll
                for (int k = 0; k < 4; ++k)
#pragma unroll
                    for (int r = 0; r < 4; ++r) {
                        uint32_t val = __hip_atomic_load(&vp[256 * k + 4 * l + r],
                                                         __ATOMIC_RELAXED,
                                                         __HIP_MEMORY_SCOPE_AGENT);
                        u[4 * k + r] = val;
                        done &= (val != SENT);
                    }
            } while (!done);
#pragma unroll
            for (int k = 0; k < 4; ++k)
                v[k] = make_float4(__uint_as_float(u[4 * k]), __uint_as_float(u[4 * k + 1]),
                                   __uint_as_float(u[4 * k + 2]), __uint_as_float(u[4 * k + 3]));
        }

        // ---- y[j] = sum_i v[i] * M[i][j] ----
        float acc = dot4(v[0], m[0]) + dot4(v[1], m[1]) + dot4(v[2], m[2]) + dot4(v[3], m[3]);
#pragma unroll
        for (int off = 32; off > 0; off >>= 1) acc += __shfl_down(acc, off, 64);

        if (l == 0) {
            uint32_t* yp = (uint32_t*)vbuf + (size_t)t * TN_D + j;
            __hip_atomic_store(yp, __float_as_uint(acc), __ATOMIC_RELAXED,
                               __HIP_MEMORY_SCOPE_AGENT);
        }

        m[0] = n[0]; m[1] = n[1]; m[2] = n[2]; m[3] = n[3];
    }

    // ---- final dot with right boundary: block 0 only ----
    if (blockIdx.x == 0) {
        const uint32_t* vp = (const uint32_t*)vbuf + (size_t)(TN_F - 1) * TN_D;
        int i0 = threadIdx.x * 4;
        uint32_t u[4];
        bool done;
        do {
            done = true;
#pragma unroll
            for (int r = 0; r < 4; ++r) {
                u[r] = __hip_atomic_load(&vp[i0 + r], __ATOMIC_RELAXED,
                                         __HIP_MEMORY_SCOPE_AGENT);
                done &= (u[r] != SENT);
            }
        } while (!done);
        float p = 0.f;
#pragma unroll
        for (int r = 0; r < 4; ++r) p += __uint_as_float(u[r]) * right[i0 + r];
#pragma unroll
        for (int off = 32; off > 0; off >>= 1) p += __shfl_down(p, off, 64);
        __shared__ float red[4];
        if (l == 0) red[w] = p;
        __syncthreads();
        if (threadIdx.x == 0) out[0] = red[0] + red[1] + red[2] + red[3];
    }
}

extern "C" void kernel_launch(void* const* d_in, const int* in_sizes, int n_in,
                              void* d_out, int out_size, void* d_ws, size_t ws_size,
                              hipStream_t stream) {
    const int* x = (const int*)d_in[0];
    const float* core = (const float*)d_in[1];
    const float* left = (const float*)d_in[2];
    const float* right = (const float*)d_in[3];
    float* out = (float*)d_out;

    const int nsym = in_sizes[1] / (TN_D * TN_D);  // 32
    const size_t coreBytes = (size_t)in_sizes[1] * sizeof(float);       // 128 MB
    const size_t vbufBytes = (size_t)TN_F * TN_D * sizeof(float);       // 4 MB

    if (ws_size >= coreBytes + vbufBytes) {
        float* coreT = (float*)d_ws;
        float* vbuf = (float*)((char*)d_ws + coreBytes);
        // ensure sentinel poison in the v-buffers regardless of first-call state
        hipMemsetAsync(vbuf, 0xAA, vbufBytes, stream);
        tn_transpose<<<dim3(32, 32, nsym), dim3(32, 8), 0, stream>>>(core, coreT);
        tn_chain<true><<<256, 256, 0, stream>>>(x, coreT, left, right, vbuf, out);
    } else {
        float* vbuf = (float*)d_ws;
        hipMemsetAsync(vbuf, 0xAA, vbufBytes, stream);
        tn_chain<false><<<256, 256, 0, stream>>>(x, core, left, right, vbuf, out);
    }
}

// Round 2
// 2781.421 us; speedup vs baseline: 2.5888x; 2.5888x over previous
//
#include <hip/hip_runtime.h>
#include <stdint.h>

#define TN_D 1024
#define TN_F 1024
#define SENT 0xAAAAAAAAu

__device__ __forceinline__ float dot4(float4 a, float4 b) {
    return a.x * b.x + a.y * b.y + a.z * b.z + a.w * b.w;
}

// ---------------------------------------------------------------------------
// Transpose core[s][i][j] -> coreT[s][j][i] so each column is contiguous.
// ---------------------------------------------------------------------------
__global__ __launch_bounds__(256) void tn_transpose(const float* __restrict__ core,
                                                    float* __restrict__ coreT) {
    __shared__ float tile[32][33];
    const int s = blockIdx.z;
    const size_t base = (size_t)s * TN_D * TN_D;
    const int j0 = blockIdx.x * 32;
    const int i0 = blockIdx.y * 32;
    const int tx = threadIdx.x;
    const int ty = threadIdx.y;
#pragma unroll
    for (int r = 0; r < 4; ++r)
        tile[ty + 8 * r][tx] = core[base + (size_t)(i0 + ty + 8 * r) * TN_D + (j0 + tx)];
    __syncthreads();
#pragma unroll
    for (int r = 0; r < 4; ++r)
        coreT[base + (size_t)(j0 + ty + 8 * r) * TN_D + (i0 + tx)] = tile[tx][ty + 8 * r];
}

template <bool TR>
__device__ __forceinline__ void load_col(const float* __restrict__ mat, int s, int j,
                                         int l, float4 m[4]) {
    if (TR) {
        const float4* mp = (const float4*)(mat + ((size_t)s * TN_D + j) * TN_D);
        m[0] = mp[l]; m[1] = mp[l + 64]; m[2] = mp[l + 128]; m[3] = mp[l + 192];
    } else {
        const float* mp = mat + (size_t)s * TN_D * TN_D + j;
#pragma unroll
        for (int k = 0; k < 4; ++k) {
            int i = 4 * l + 256 * k;
            m[k] = make_float4(mp[(size_t)i * TN_D], mp[(size_t)(i + 1) * TN_D],
                               mp[(size_t)(i + 2) * TN_D], mp[(size_t)(i + 3) * TN_D]);
        }
    }
}

// Spin until the 4 dwords at vp are all != sentinel; only missing entries are
// re-loaded (straggler polls touch a few dwords, not the whole vector).
__device__ __forceinline__ float4 poll4(const uint32_t* vp) {
    uint32_t u[4];
#pragma unroll
    for (int r = 0; r < 4; ++r)
        u[r] = __hip_atomic_load(vp + r, __ATOMIC_RELAXED, __HIP_MEMORY_SCOPE_AGENT);
    bool done = (u[0] != SENT) & (u[1] != SENT) & (u[2] != SENT) & (u[3] != SENT);
    while (!done) {
        done = true;
#pragma unroll
        for (int r = 0; r < 4; ++r)
            if (u[r] == SENT) {
                u[r] = __hip_atomic_load(vp + r, __ATOMIC_RELAXED, __HIP_MEMORY_SCOPE_AGENT);
                done &= (u[r] != SENT);
            }
    }
    return make_float4(__uint_as_float(u[0]), __uint_as_float(u[1]),
                       __uint_as_float(u[2]), __uint_as_float(u[3]));
}

// ---------------------------------------------------------------------------
// Persistent chain kernel. 256 blocks x 256 threads (4 waves); wave w of
// block b owns column j = 4b + w. Per step: block cooperatively pulls v_t
// into LDS (each thread spins only on its own 4 dwords), one barrier,
// each wave dots its register-resident matrix column against LDS v.
// ---------------------------------------------------------------------------
template <bool TR>
__global__ __launch_bounds__(256, 1) void tn_chain(const int* __restrict__ x,
                                                   const float* __restrict__ mat,
                                                   const float* __restrict__ left,
                                                   const float* __restrict__ right,
                                                   float* __restrict__ vbuf,
                                                   float* __restrict__ out) {
    __shared__ float4 lv[2][TN_D / 4];  // double-buffered v
    __shared__ float red[4];
    const int tid = threadIdx.x;
    const int w = tid >> 6;
    const int l = tid & 63;
    const int j = blockIdx.x * 4 + w;

    float4 m[4];
    load_col<TR>(mat, x[0], j, l, m);

    for (int t = 0; t < TN_F; ++t) {
        // prefetch next step's column before waiting (latency hides under spin)
        float4 n[4];
        load_col<TR>(mat, x[(t + 1 < TN_F) ? t + 1 : 0], j, l, n);

        if (t == 0) {
            lv[0][tid] = ((const float4*)left)[tid];
        } else {
            const uint32_t* vp = (const uint32_t*)vbuf + (size_t)(t - 1) * TN_D + 4 * tid;
            lv[t & 1][tid] = poll4(vp);
        }
        __syncthreads();

        const float4* vv = lv[t & 1];
        float acc = dot4(vv[l], m[0]) + dot4(vv[l + 64], m[1]) +
                    dot4(vv[l + 128], m[2]) + dot4(vv[l + 192], m[3]);
#pragma unroll
        for (int off = 32; off > 0; off >>= 1) acc += __shfl_down(acc, off, 64);

        if (l == 0)
            __hip_atomic_store((uint32_t*)vbuf + (size_t)t * TN_D + j,
                               __float_as_uint(acc), __ATOMIC_RELAXED,
                               __HIP_MEMORY_SCOPE_AGENT);

        m[0] = n[0]; m[1] = n[1]; m[2] = n[2]; m[3] = n[3];
    }

    // ---- final dot with right boundary: block 0 only ----
    if (blockIdx.x == 0) {
        const uint32_t* vp = (const uint32_t*)vbuf + (size_t)(TN_F - 1) * TN_D + 4 * tid;
        float4 v = poll4(vp);
        const float4 r4 = ((const float4*)right)[tid];
        float p = dot4(v, r4);
#pragma unroll
        for (int off = 32; off > 0; off >>= 1) p += __shfl_down(p, off, 64);
        if (l == 0) red[w] = p;
        __syncthreads();
        if (tid == 0) out[0] = red[0] + red[1] + red[2] + red[3];
    }
}

extern "C" void kernel_launch(void* const* d_in, const int* in_sizes, int n_in,
                              void* d_out, int out_size, void* d_ws, size_t ws_size,
                              hipStream_t stream) {
    const int* x = (const int*)d_in[0];
    const float* core = (const float*)d_in[1];
    const float* left = (const float*)d_in[2];
    const float* right = (const float*)d_in[3];
    float* out = (float*)d_out;

    const int nsym = in_sizes[1] / (TN_D * TN_D);
    const size_t coreBytes = (size_t)in_sizes[1] * sizeof(float);
    const size_t vbufBytes = (size_t)TN_F * TN_D * sizeof(float);

    if (ws_size >= coreBytes + vbufBytes) {
        float* coreT = (float*)d_ws;
        float* vbuf = (float*)((char*)d_ws + coreBytes);
        hipMemsetAsync(vbuf, 0xAA, vbufBytes, stream);
        tn_transpose<<<dim3(32, 32, nsym), dim3(32, 8), 0, stream>>>(core, coreT);
        tn_chain<true><<<256, 256, 0, stream>>>(x, coreT, left, right, vbuf, out);
    } else {
        float* vbuf = (float*)d_ws;
        hipMemsetAsync(vbuf, 0xAA, vbufBytes, stream);
        tn_chain<false><<<256, 256, 0, stream>>>(x, core, left, right, vbuf, out);
    }
}